// Round 1
// baseline (96.363 us; speedup 1.0000x reference)
//
#include <hip/hip_runtime.h>

// GaussianEdgeGuideV2: edge-guided 3x3 softmax filtering.
// mask: (8,64,128,128) fp32, edge: (8,1,64,64) fp32 -> out (8,64,128,128) fp32.
// Memory-bound: ~67 MB HBM traffic -> ~10.6 us floor at 6.3 TB/s.

#define THETA 10.0f

constexpr int NB = 8;     // batch
constexpr int C  = 64;    // mask channels
constexpr int H  = 128, W = 128;
constexpr int EH = 64,  EW = 64;

constexpr int ROWS = 8;   // output rows per block tile
constexpr int CG   = 8;   // channels per block (64/CG groups)

// grid: x = H/ROWS = 16, y = C/CG = 8, z = NB = 8; block = 256
__global__ __launch_bounds__(256) void geg_kernel(
    const float* __restrict__ mask,
    const float* __restrict__ edge,
    float* __restrict__ out)
{
    // upsampled-edge tile with zero border (the unfold's zero padding)
    __shared__ float e_s[ROWS + 2][W + 4];   // use stride W+4; fill/read cols 0..W+1

    const int t     = threadIdx.x;
    const int ytile = blockIdx.x;
    const int cg    = blockIdx.y;
    const int n     = blockIdx.z;
    const int y0    = ytile * ROWS;

    // ---- stage bilinear-upsampled edge rows [y0-1, y0+ROWS] x cols [-1, W]
    const float* eg = edge + n * (EH * EW);
    const float s = 63.0f / 127.0f;          // (EH-1)/(H-1), fp32 like the reference
    for (int idx = t; idx < (ROWS + 2) * (W + 2); idx += 256) {
        int r  = idx / (W + 2);
        int cc = idx - r * (W + 2);
        int gy = y0 - 1 + r;
        int gx = cc - 1;
        float v = 0.0f;
        if (gy >= 0 && gy < H && gx >= 0 && gx < W) {
            float ys = gy * s;
            float xs = gx * s;
            float yf = floorf(ys), xf = floorf(xs);
            int iy0 = (int)yf, ix0 = (int)xf;
            int iy1 = min(iy0 + 1, EH - 1), ix1 = min(ix0 + 1, EW - 1);
            float wy = ys - yf, wx = xs - xf;
            float tl = eg[iy0 * EW + ix0], tr = eg[iy0 * EW + ix1];
            float bl = eg[iy1 * EW + ix0], br = eg[iy1 * EW + ix1];
            float lv = tl + (bl - tl) * wy;
            float rv = tr + (br - tr) * wy;
            v = lv + (rv - lv) * wx;
        }
        e_s[r][cc] = v;
    }
    __syncthreads();

    // ---- each thread: 4 consecutive-x pixels in one row
    const int x4 = (t & 31) * 4;     // 0,4,...,124
    const int r  = t >> 5;           // 0..7
    const int gy = y0 + r;

    // per-pixel softmax weights (OOB neighbors zeroed; denom keeps all 9 terms)
    float w[4][9];
    #pragma unroll
    for (int p = 0; p < 4; ++p) {
        const int gx = x4 + p;
        const float c = e_s[r + 1][gx + 1];
        float a[9], sum = 0.0f;
        #pragma unroll
        for (int di = 0; di < 3; ++di) {
            #pragma unroll
            for (int dj = 0; dj < 3; ++dj) {
                float d = c - e_s[r + di][gx + dj];
                float e = __expf(-THETA * d * d);
                a[di * 3 + dj] = e;
                sum += e;
            }
        }
        const float inv = 1.0f / sum;
        #pragma unroll
        for (int di = 0; di < 3; ++di) {
            #pragma unroll
            for (int dj = 0; dj < 3; ++dj) {
                int ny = gy + di - 1, nx = gx + dj - 1;
                bool ok = (ny >= 0) & (ny < H) & (nx >= 0) & (nx < W);
                w[p][di * 3 + dj] = ok ? a[di * 3 + dj] * inv : 0.0f;
            }
        }
    }

    // clamped element offsets inside one channel plane (OOB weights are 0,
    // so clamped reads are harmless and keep addresses in-bounds)
    int rowoff[3];
    rowoff[0] = max(gy - 1, 0) * W;
    rowoff[1] = gy * W;
    rowoff[2] = min(gy + 1, H - 1) * W;
    int coloff[6];
    #pragma unroll
    for (int j = 0; j < 6; ++j) coloff[j] = min(max(x4 - 1 + j, 0), W - 1);

    int off[3][6];
    #pragma unroll
    for (int i = 0; i < 3; ++i)
        #pragma unroll
        for (int j = 0; j < 6; ++j) off[i][j] = rowoff[i] + coloff[j];

    const int c0 = cg * CG;
    const float* mptr = mask + (size_t)(n * C + c0) * (H * W);
    float*       optr = out  + (size_t)(n * C + c0) * (H * W) + gy * W + x4;

    for (int ci = 0; ci < CG; ++ci) {
        float m[3][6];
        #pragma unroll
        for (int i = 0; i < 3; ++i)
            #pragma unroll
            for (int j = 0; j < 6; ++j)
                m[i][j] = mptr[off[i][j]];   // SGPR base + VGPR offset

        float av[4];
        #pragma unroll
        for (int p = 0; p < 4; ++p) {
            float acc = 0.0f;
            #pragma unroll
            for (int i = 0; i < 3; ++i)
                #pragma unroll
                for (int j = 0; j < 3; ++j)
                    acc += m[i][p + j] * w[p][i * 3 + j];
            av[p] = acc;
        }
        *(float4*)optr = make_float4(av[0], av[1], av[2], av[3]);
        mptr += H * W;
        optr += H * W;
    }
}

extern "C" void kernel_launch(void* const* d_in, const int* in_sizes, int n_in,
                              void* d_out, int out_size, void* d_ws, size_t ws_size,
                              hipStream_t stream) {
    const float* mask = (const float*)d_in[0];
    const float* edge = (const float*)d_in[1];
    float* out = (float*)d_out;

    dim3 grid(H / ROWS, C / CG, NB);   // 16 x 8 x 8 = 1024 blocks
    dim3 block(256);
    geg_kernel<<<grid, block, 0, stream>>>(mask, edge, out);
}

// Round 2
// 85.099 us; speedup vs baseline: 1.1324x; 1.1324x over previous
//
#include <hip/hip_runtime.h>

// GaussianEdgeGuideV2: edge-guided 3x3 softmax filtering.
// mask: (8,64,128,128) fp32, edge: (8,1,64,64) fp32 -> out (8,64,128,128) fp32.
// Memory-bound: ~67 MB mandatory HBM traffic -> ~10.6 us floor at 6.3 TB/s.
//
// R2: channel loop uses 3 coalesced dwordx4 row loads + 2 shuffles/row for the
// x-halo (was 18 scalar stride-16B loads), plus next-channel prefetch.
// Grid order (cg fastest) puts adjacent y-tiles on the same XCD for halo L2 reuse.

#define THETA 10.0f

constexpr int NB = 8;     // batch
constexpr int C  = 64;    // mask channels
constexpr int H  = 128, W = 128;
constexpr int EH = 64,  EW = 64;

constexpr int ROWS = 8;   // output rows per block tile
constexpr int CG   = 8;   // channels per block (64/CG groups)

// grid: x = C/CG = 8, y = H/ROWS = 16, z = NB = 8; block = 256
__global__ __launch_bounds__(256) void geg_kernel(
    const float* __restrict__ mask,
    const float* __restrict__ edge,
    float* __restrict__ out)
{
    // upsampled-edge tile with zero border (the unfold's zero padding)
    __shared__ float e_s[ROWS + 2][W + 4];   // fill/read cols 0..W+1

    const int t     = threadIdx.x;
    const int cg    = blockIdx.x;
    const int ytile = blockIdx.y;
    const int n     = blockIdx.z;
    const int y0    = ytile * ROWS;

    // ---- stage bilinear-upsampled edge rows [y0-1, y0+ROWS] x cols [-1, W]
    const float* eg = edge + n * (EH * EW);
    const float s = 63.0f / 127.0f;          // (EH-1)/(H-1)
    for (int idx = t; idx < (ROWS + 2) * (W + 2); idx += 256) {
        int r  = idx / (W + 2);
        int cc = idx - r * (W + 2);
        int gy = y0 - 1 + r;
        int gx = cc - 1;
        float v = 0.0f;
        if (gy >= 0 && gy < H && gx >= 0 && gx < W) {
            float ys = gy * s;
            float xs = gx * s;
            float yf = floorf(ys), xf = floorf(xs);
            int iy0 = (int)yf, ix0 = (int)xf;
            int iy1 = min(iy0 + 1, EH - 1), ix1 = min(ix0 + 1, EW - 1);
            float wy = ys - yf, wx = xs - xf;
            float tl = eg[iy0 * EW + ix0], tr = eg[iy0 * EW + ix1];
            float bl = eg[iy1 * EW + ix0], br = eg[iy1 * EW + ix1];
            float lv = tl + (bl - tl) * wy;
            float rv = tr + (br - tr) * wy;
            v = lv + (rv - lv) * wx;
        }
        e_s[r][cc] = v;
    }
    __syncthreads();

    // ---- each thread: 4 consecutive-x pixels in one row
    const int lane = t & 31;         // position within the row group
    const int x4   = lane * 4;       // 0,4,...,124
    const int r    = t >> 5;         // 0..7
    const int gy   = y0 + r;

    // per-pixel softmax weights (OOB neighbors zeroed; denom keeps all 9 terms)
    float w[4][9];
    #pragma unroll
    for (int p = 0; p < 4; ++p) {
        const int gx = x4 + p;
        const float c = e_s[r + 1][gx + 1];
        float a[9], sum = 0.0f;
        #pragma unroll
        for (int di = 0; di < 3; ++di) {
            #pragma unroll
            for (int dj = 0; dj < 3; ++dj) {
                float d = c - e_s[r + di][gx + dj];
                float e = __expf(-THETA * d * d);
                a[di * 3 + dj] = e;
                sum += e;
            }
        }
        const float inv = 1.0f / sum;
        #pragma unroll
        for (int di = 0; di < 3; ++di) {
            #pragma unroll
            for (int dj = 0; dj < 3; ++dj) {
                int ny = gy + di - 1, nx = gx + dj - 1;
                bool ok = (ny >= 0) & (ny < H) & (nx >= 0) & (nx < W);
                w[p][di * 3 + dj] = ok ? a[di * 3 + dj] * inv : 0.0f;
            }
        }
    }

    // clamped row offsets (OOB rows have zero weight; clamp keeps addr in-bounds)
    int rowoff[3];
    rowoff[0] = max(gy - 1, 0) * W + x4;
    rowoff[1] = gy * W + x4;
    rowoff[2] = min(gy + 1, H - 1) * W + x4;

    const int c0 = cg * CG;
    const float* mptr = mask + (size_t)(n * C + c0) * (H * W);
    float*       optr = out  + (size_t)(n * C + c0) * (H * W) + gy * W + x4;

    float4 cur[3];
    #pragma unroll
    for (int i = 0; i < 3; ++i) cur[i] = *(const float4*)(mptr + rowoff[i]);

    #pragma unroll
    for (int ci = 0; ci < CG; ++ci) {
        float4 nxt[3];
        if (ci + 1 < CG) {
            #pragma unroll
            for (int i = 0; i < 3; ++i)
                nxt[i] = *(const float4*)(mptr + H * W + rowoff[i]);
        }

        float av[4] = {0.f, 0.f, 0.f, 0.f};
        #pragma unroll
        for (int i = 0; i < 3; ++i) {
            // 6-wide row window: halo elements via cross-lane shuffle within
            // the 32-lane row group (edge lanes get junk, but their weight is 0)
            float m6[6];
            m6[0] = __shfl_up(cur[i].w, 1, 32);
            m6[1] = cur[i].x; m6[2] = cur[i].y; m6[3] = cur[i].z; m6[4] = cur[i].w;
            m6[5] = __shfl_down(cur[i].x, 1, 32);
            #pragma unroll
            for (int p = 0; p < 4; ++p) {
                av[p] = fmaf(m6[p + 0], w[p][i * 3 + 0],
                        fmaf(m6[p + 1], w[p][i * 3 + 1],
                        fmaf(m6[p + 2], w[p][i * 3 + 2], av[p])));
            }
        }
        *(float4*)optr = make_float4(av[0], av[1], av[2], av[3]);

        #pragma unroll
        for (int i = 0; i < 3; ++i) cur[i] = nxt[i];
        mptr += H * W;
        optr += H * W;
    }
}

extern "C" void kernel_launch(void* const* d_in, const int* in_sizes, int n_in,
                              void* d_out, int out_size, void* d_ws, size_t ws_size,
                              hipStream_t stream) {
    const float* mask = (const float*)d_in[0];
    const float* edge = (const float*)d_in[1];
    float* out = (float*)d_out;

    dim3 grid(C / CG, H / ROWS, NB);   // 8 x 16 x 8 = 1024 blocks
    dim3 block(256);
    geg_kernel<<<grid, block, 0, stream>>>(mask, edge, out);
}